// Round 4
// baseline (632.380 us; speedup 1.0000x reference)
//
#include <hip/hip_runtime.h>

typedef short short8 __attribute__((ext_vector_type(8)));
typedef float f32x4 __attribute__((ext_vector_type(4)));
typedef float fv2 __attribute__((ext_vector_type(2)));
typedef unsigned int u32;

#define HDIM 128
#define NSPLIT 32
#define NRANGE 8        // column ranges of 4096 (30000>>12 = 7 max) -> 2 MB Wn slice/range
#define CAPR 16         // per-(row,range) capacity; Poisson(2), P(>16) ~ 5e-11/bucket

#define AS1 __attribute__((address_space(1)))
#define AS3 __attribute__((address_space(3)))

__device__ __forceinline__ void gload16(const void* g, void* l) {
  __builtin_amdgcn_global_load_lds((AS1 const u32*)g, (AS3 u32*)l, 16, 0, 0);
}

__device__ __forceinline__ unsigned short f2bf(float x) {
  unsigned int u = __float_as_uint(x);
  unsigned int r = (u + 0x7fffu + ((u >> 16) & 1u)) >> 16;
  return (unsigned short)r;
}
__device__ __forceinline__ float bf2f(unsigned short b) {
  return __uint_as_float(((unsigned int)b) << 16);
}

#define MFMA(a, b, c) __builtin_amdgcn_mfma_f32_16x16x32_bf16(a, b, c, 0, 0, 0)

// ---------------------------------------------------------------------------
// 1) bucket placement, range-split: p = atomicAdd(cnt[r*8 + (c>>12)]);
//    se[((r*8+rng)*CAPR)+p] = {c, v}. Same single-pass structure as before
//    (plain stores; R1 showed nt hints push se to HBM), but edges land
//    pre-sorted by column range so the gather can phase its Wn working set.
//    Atomic contention also drops 8x (480K atomics over 240K counters).
// ---------------------------------------------------------------------------
__global__ __launch_bounds__(256) void bucket_kernel(
    const int* __restrict__ r0, const int* __restrict__ c0, const float* __restrict__ v0,
    const int* __restrict__ r1, const int* __restrict__ c1, const float* __restrict__ v1,
    int* __restrict__ cnt0, int* __restrict__ cnt1,
    int2* __restrict__ se0, int2* __restrict__ se1, int E)
{
  int t = blockIdx.x * 256 + threadIdx.x;
  if (t < E) {
    int r = r0[t], c = c0[t];
    int b = r * NRANGE + (c >> 12);
    int p = atomicAdd(&cnt0[b], 1);
    if (p < CAPR) se0[(size_t)b * CAPR + p] = make_int2(c, __float_as_int(v0[t]));
  } else if (t < 2 * E) {
    int e = t - E;
    int r = r1[e], c = c1[e];
    int b = r * NRANGE + (c >> 12);
    int p = atomicAdd(&cnt1[b], 1);
    if (p < CAPR) se1[(size_t)b * CAPR + p] = make_int2(c, __float_as_int(v1[e]));
  }
}

// ---------------------------------------------------------------------------
// 2) FUSED gather + LN + bf16 hi/lo pack, column-range phased.
//    One wave per vocab row; lane owns cols h=2*lane, 2*lane+1.
//    Range loop p=0..7: all concurrently-running waves gather from the SAME
//    2 MB Wn slice -> L2-resident (vs ~74% L3 misses on the unphased 15.4 MB
//    working set). Edge gather count unchanged (each edge visited once).
//    LN + packing identical to R3 (summation order differs only by the
//    range-sort of edges; fp32-assoc-level drift).
// ---------------------------------------------------------------------------
__global__ __launch_bounds__(1024) void fused_glp_kernel(
    const float* __restrict__ Wn0, const float* __restrict__ Wn1,
    const float* __restrict__ W0s, const float* __restrict__ W1s,
    const int* __restrict__ cnt0, const int2* __restrict__ se0,
    const int* __restrict__ cnt1, const int2* __restrict__ se1,
    const float* __restrict__ gamma, const float* __restrict__ beta,
    unsigned short* __restrict__ ph, unsigned short* __restrict__ pl, int V)
{
  __shared__ __align__(16) unsigned short lh[2048];   // 4 KB hi half-tile
  __shared__ __align__(16) unsigned short ll[2048];   // 4 KB lo half-tile
  int t = threadIdx.x;
  int wv = t >> 6, lane = t & 63;
  int g = blockIdx.x >> 1, hs = blockIdx.x & 1;

  if (t < 256)      ((f32x4*)lh)[t] = (f32x4)(0.f);
  else if (t < 512) ((f32x4*)ll)[t - 256] = (f32x4)(0.f);
  __syncthreads();

  int v = g * 32 + hs * 16 + wv;
  int h = lane * 2;
  if (v < V) {
    fv2 gm = ((const fv2*)gamma)[lane];
    fv2 bt = ((const fv2*)beta)[lane];
    float ry0 = 0.f, ry1 = 0.f;
    #pragma unroll
    for (int br = 0; br < 2; ++br) {
      const float* Wn = br ? Wn1 : Wn0;
      const float* Ws = br ? W1s : W0s;
      const int* cnt  = br ? cnt1 : cnt0;
      const int2* se  = br ? se1 : se0;
      float a0 = 0.f, a1 = 0.f, dsum = 0.f;
      for (int p = 0; p < NRANGE; ++p) {
        int b = v * NRANGE + p;
        int n = cnt[b]; if (n > CAPR) n = CAPR;
        const int2* sep = se + (size_t)b * CAPR;
        int i = 0;
        for (; i + 4 <= n; i += 4) {
          int2 e0 = sep[i], e1 = sep[i + 1], e2 = sep[i + 2], e3 = sep[i + 3];
          fv2 w0 = ((const fv2*)(Wn + (size_t)e0.x * HDIM))[lane];
          fv2 w1 = ((const fv2*)(Wn + (size_t)e1.x * HDIM))[lane];
          fv2 w2 = ((const fv2*)(Wn + (size_t)e2.x * HDIM))[lane];
          fv2 w3 = ((const fv2*)(Wn + (size_t)e3.x * HDIM))[lane];
          float f0 = __int_as_float(e0.y), f1 = __int_as_float(e1.y);
          float f2 = __int_as_float(e2.y), f3 = __int_as_float(e3.y);
          dsum += (f0 + f1) + (f2 + f3);
          a0 = fmaf(f0, w0.x, a0); a1 = fmaf(f0, w0.y, a1);
          a0 = fmaf(f1, w1.x, a0); a1 = fmaf(f1, w1.y, a1);
          a0 = fmaf(f2, w2.x, a0); a1 = fmaf(f2, w2.y, a1);
          a0 = fmaf(f3, w3.x, a0); a1 = fmaf(f3, w3.y, a1);
        }
        for (; i < n; ++i) {
          int2 e0 = sep[i];
          fv2 w0 = ((const fv2*)(Wn + (size_t)e0.x * HDIM))[lane];
          float f0 = __int_as_float(e0.y);
          dsum += f0;
          a0 = fmaf(f0, w0.x, a0); a1 = fmaf(f0, w0.y, a1);
        }
      }
      float invd = 1.0f / fmaxf(dsum, 1.0f);
      fv2 ww = ((const fv2*)(Ws + (size_t)v * HDIM))[lane];
      float x0 = fmaxf(fmaf(a0, invd, ww.x), 0.f);
      float x1 = fmaxf(fmaf(a1, invd, ww.y), 0.f);
      float sum = x0 + x1;
      #pragma unroll
      for (int off = 32; off; off >>= 1) sum += __shfl_xor(sum, off, 64);
      float mu = sum * (1.0f / 128.0f);
      float d0 = x0 - mu, d1 = x1 - mu;
      float q = d0 * d0 + d1 * d1;
      #pragma unroll
      for (int off = 32; off; off >>= 1) q += __shfl_xor(q, off, 64);
      float rstd = rsqrtf(q * (1.0f / 128.0f) + 1e-5f);
      ry0 += d0 * rstd * gm.x + bt.x;
      ry1 += d1 * rstd * gm.y + bt.y;
    }
    // local scatter into half-tile: full-group slot = tt*512 + l*8 + j with
    // l = qq*16 + (h&15), qq = r>>3, j = r&7, r = hs*16+wv; half-local form:
    int tt = lane >> 3;
    int loc = tt * 256 + ((wv >> 3) * 16 + (h & 15)) * 8 + (wv & 7);
    unsigned short h0 = f2bf(ry0);
    unsigned short l0 = f2bf(ry0 - bf2f(h0));
    unsigned short h1 = f2bf(ry1);
    unsigned short l1 = f2bf(ry1 - bf2f(h1));
    lh[loc] = h0;     ll[loc] = l0;
    lh[loc + 8] = h1; ll[loc + 8] = l1;
  }
  __syncthreads();

  // coalesced write-out: half-tile chunk c (16B) -> global chunk
  //   g*512 + (c>>5)*32 + hs*32 + c     (512 B runs, 512 B stride)
  if (t < 512) {
    int arr = t >> 8;            // 0: ph, 1: pl
    int c = t & 255;
    size_t chunk = (size_t)g * 512 + (size_t)(((c >> 5) + hs) * 32 + c);
    f32x4 val = arr ? ((const f32x4*)ll)[c] : ((const f32x4*)lh)[c];
    f32x4* dst = arr ? (f32x4*)pl : (f32x4*)ph;
    dst[chunk] = val;
  }
}

__device__ __forceinline__ void cvt8hi(float4 a0, float4 a1, short8& hi) {
  float vv[8] = {a0.x, a0.y, a0.z, a0.w, a1.x, a1.y, a1.z, a1.w};
  #pragma unroll
  for (int j = 0; j < 8; ++j) hi[j] = (short)f2bf(vv[j]);
}

// ---------------------------------------------------------------------------
// 3) MFMA GEMM: global_load_lds(16B) staging of X (fp32, chunk-XOR swizzled)
//    and pre-packed B hi/lo, double-buffered LDS. 2-term split:
//    X(bf16) x (B_hi + B_lo). BM=128, BN=128, K-step 32. Split-K into P.
//    (unchanged)
// ---------------------------------------------------------------------------
__global__ __launch_bounds__(256, 2) void gemm_kernel(
    const float* __restrict__ X, const unsigned short* __restrict__ ph,
    const unsigned short* __restrict__ pl, float* __restrict__ P,
    int M, int K, int groups, int gps)
{
  __shared__ __align__(16) float Xl[2][128 * 32];            // 16 KB each
  __shared__ __align__(16) unsigned short Bl[2][2][4096];    // hi/lo, 8 KB each
  int t = threadIdx.x;
  int w = t >> 6, lane = t & 63;
  int m0 = blockIdx.x * 128;
  int g0 = blockIdx.y * gps;
  int g1 = g0 + gps; if (g1 > groups) g1 = groups;
  int q = lane >> 4;

  int xr = w * 32 + (lane >> 3);          // local row for staging call j=0 (+8j)
  int xc = lane & 7;                      // 16B chunk index
  int swz = ((xc ^ (xr & 7)) << 2);

  f32x4 acc[2][8];
  #pragma unroll
  for (int rt = 0; rt < 2; ++rt)
    #pragma unroll
    for (int ct = 0; ct < 8; ++ct) acc[rt][ct] = (f32x4)(0.f);

  auto stageX = [&](int g, int buf) {
    int kf = g * 32 + swz;
    bool ok = (kf + 4 <= K);
    const float* rbase = X + (size_t)(m0 + xr) * K + kf;
    #pragma unroll
    for (int j = 0; j < 4; ++j) {
      const float* gp = ok ? (rbase + (size_t)(8 * j) * K) : X;
      gload16(gp, &Xl[buf][(w * 32 + 8 * j) * 32]);
    }
  };
  auto stageB = [&](int g, int buf) {
    const unsigned short* gh = ph + (size_t)g * 4096 + (w * 2) * 512 + lane * 8;
    const unsigned short* gl = pl + (size_t)g * 4096 + (w * 2) * 512 + lane * 8;
    #pragma unroll
    for (int j = 0; j < 2; ++j) {
      gload16(gh + j * 512, &Bl[buf][0][(w * 2 + j) * 512]);
      gload16(gl + j * 512, &Bl[buf][1][(w * 2 + j) * 512]);
    }
  };

  if (g0 < g1) { stageX(g0, 0); stageB(g0, 0); }
  __syncthreads();

  for (int g = g0; g < g1; ++g) {
    int buf = (g - g0) & 1;
    if (g + 1 < g1) { stageX(g + 1, buf ^ 1); stageB(g + 1, buf ^ 1); }
    short8 ah[2];
    #pragma unroll
    for (int rt = 0; rt < 2; ++rt) {
      int arow = w * 32 + rt * 16 + (lane & 15);
      int sx = arow & 7;
      float4 a0 = *(const float4*)&Xl[buf][arow * 32 + (((2 * q) ^ sx) << 2)];
      float4 a1 = *(const float4*)&Xl[buf][arow * 32 + ((((2 * q) | 1) ^ sx) << 2)];
      cvt8hi(a0, a1, ah[rt]);
    }
    #pragma unroll
    for (int ct = 0; ct < 8; ++ct) {
      short8 bh = *(const short8*)&Bl[buf][0][ct * 512 + lane * 8];
      short8 bl = *(const short8*)&Bl[buf][1][ct * 512 + lane * 8];
      #pragma unroll
      for (int rt = 0; rt < 2; ++rt) {
        acc[rt][ct] = MFMA(ah[rt], bh, acc[rt][ct]);
        acc[rt][ct] = MFMA(ah[rt], bl, acc[rt][ct]);
      }
    }
    __syncthreads();
  }

  float* pp = P + (size_t)blockIdx.y * ((size_t)M * 128);
  #pragma unroll
  for (int rt = 0; rt < 2; ++rt) {
    #pragma unroll
    for (int ct = 0; ct < 8; ++ct) {
      int n = ct * 16 + (lane & 15);
      #pragma unroll
      for (int r = 0; r < 4; ++r) {
        int m = m0 + w * 32 + rt * 16 + (lane >> 4) * 4 + r;
        pp[(size_t)m * 128 + n] = acc[rt][ct][r];
      }
    }
  }
}

// ---------------------------------------------------------------------------
// 4) fused split-K reduce + fc: T-row segment reduced in registers (same
//    s=0..S order -> bit-identical), staged through LDS, then
//    out = T @ fc_W + fc_b. (unchanged)
// ---------------------------------------------------------------------------
__global__ __launch_bounds__(256) void fc_kernel(
    const float* __restrict__ P, const float* __restrict__ W,
    const float* __restrict__ bias, float* __restrict__ out, int n, int S)
{
  __shared__ float Wl[HDIM * HDIM];   // 64 KB
  __shared__ float Tl[16 * HDIM];     // 8 KB
  int t = threadIdx.x;
  const float4* Wv = (const float4*)W;
  float4* Wlv = (float4*)Wl;
  #pragma unroll
  for (int i = t; i < HDIM * HDIM / 4; i += 256) Wlv[i] = Wv[i];

  int m_loc = t >> 4;                 // 0..15
  int o = (t & 15) << 3;              // 0,8,..,120
  int m = blockIdx.x * 16 + m_loc;
  size_t base = (size_t)m * HDIM + o;

  float4 tv0 = make_float4(0.f, 0.f, 0.f, 0.f);
  float4 tv1 = make_float4(0.f, 0.f, 0.f, 0.f);
  for (int s = 0; s < S; ++s) {
    const float4* pr = (const float4*)(P + (size_t)s * n + base);
    float4 a = pr[0], b = pr[1];
    tv0.x += a.x; tv0.y += a.y; tv0.z += a.z; tv0.w += a.w;
    tv1.x += b.x; tv1.y += b.y; tv1.z += b.z; tv1.w += b.w;
  }
  ((float4*)&Tl[m_loc * HDIM + o])[0] = tv0;
  ((float4*)&Tl[m_loc * HDIM + o])[1] = tv1;
  __syncthreads();

  float acc[8];
  #pragma unroll
  for (int j = 0; j < 8; ++j) acc[j] = bias[o + j];
  const float* Trow = Tl + m_loc * HDIM;
  for (int k = 0; k < HDIM; ++k) {
    float a = Trow[k];
    const float* wr = &Wl[k * HDIM + o];
    #pragma unroll
    for (int j = 0; j < 8; ++j) acc[j] = fmaf(a, wr[j], acc[j]);
  }
  float* orow = out + (size_t)m * HDIM + o;
  #pragma unroll
  for (int j = 0; j < 8; ++j) orow[j] = acc[j];
}

// ---------------------------------------------------------------------------
extern "C" void kernel_launch(void* const* d_in, const int* in_sizes, int n_in,
                              void* d_out, int out_size, void* d_ws, size_t ws_size,
                              hipStream_t stream) {
  const float* X   = (const float*)d_in[0];
  const float* W0s = (const float*)d_in[1];
  const float* W0n = (const float*)d_in[2];
  const float* W1s = (const float*)d_in[3];
  const float* W1n = (const float*)d_in[4];
  const int*   r0  = (const int*)d_in[5];
  const int*   c0  = (const int*)d_in[6];
  const float* v0  = (const float*)d_in[7];
  const int*   r1  = (const int*)d_in[8];
  const int*   c1  = (const int*)d_in[9];
  const float* v1  = (const float*)d_in[10];
  const float* gam = (const float*)d_in[11];
  const float* bet = (const float*)d_in[12];
  const float* fcW = (const float*)d_in[13];
  const float* fcb = (const float*)d_in[14];
  float* out = (float*)d_out;

  const int H = HDIM;
  const int V = in_sizes[1] / H;     // 30000
  const int B = in_sizes[0] / V;     // 2048
  const int E = in_sizes[5];         // 480000
  const int groups = (V + 31) / 32;  // 938

  // workspace layout
  char* p = (char*)d_ws;
  int*   cnt0 = (int*)p;               p += (size_t)V * NRANGE * 4;  // memset covers both
  int*   cnt1 = (int*)p;               p += (size_t)V * NRANGE * 4;
  unsigned short* ph = (unsigned short*)p;  p += (size_t)groups * 4096 * 2;
  unsigned short* pl = (unsigned short*)p;  p += (size_t)groups * 4096 * 2;
  // region2: range-bucketed se (2 x 30.7 MB), later aliased by split-K P
  char*  region2 = p;
  int2*  se0    = (int2*)region2;                                  // V*NRANGE*CAPR*8
  int2*  se1    = se0 + (size_t)V * NRANGE * CAPR;                 // V*NRANGE*CAPR*8
  float* P      = (float*)region2;     // NSPLIT*B*H*4 = 33.6 MB aliases se

  const int S = NSPLIT;
  const int gps = (groups + S - 1) / S;

  hipMemsetAsync(cnt0, 0, (size_t)V * NRANGE * 2 * 4, stream);

  int eblocks = (2 * E + 255) / 256;
  bucket_kernel<<<eblocks, 256, 0, stream>>>(r0, c0, v0, r1, c1, v1,
                                             cnt0, cnt1, se0, se1, E);
  int fblocks = groups * 2;            // half-groups of 16 rows
  fused_glp_kernel<<<fblocks, 1024, 0, stream>>>(W0n, W1n, W0s, W1s,
                                                 cnt0, se0, cnt1, se1,
                                                 gam, bet, ph, pl, V);
  dim3 ggrid(B / 128, S);
  gemm_kernel<<<ggrid, 256, 0, stream>>>(X, ph, pl, P, B, V, groups, gps);
  fc_kernel<<<B / 16, 256, 0, stream>>>(P, fcW, fcb, out, B * H, S);
}

// Round 5
// 579.347 us; speedup vs baseline: 1.0915x; 1.0915x over previous
//
#include <hip/hip_runtime.h>

typedef short short8 __attribute__((ext_vector_type(8)));
typedef float f32x4 __attribute__((ext_vector_type(4)));
typedef float fv2 __attribute__((ext_vector_type(2)));
typedef unsigned int u32;

#define HDIM 128
#define NSPLIT 32
#define CAP 64          // bucket capacity per row; rows ~Poisson(16), P(>64) ~ 1e-20

#define AS1 __attribute__((address_space(1)))
#define AS3 __attribute__((address_space(3)))

__device__ __forceinline__ void gload16(const void* g, void* l) {
  __builtin_amdgcn_global_load_lds((AS1 const u32*)g, (AS3 u32*)l, 16, 0, 0);
}

__device__ __forceinline__ unsigned short f2bf(float x) {
  unsigned int u = __float_as_uint(x);
  unsigned int r = (u + 0x7fffu + ((u >> 16) & 1u)) >> 16;
  return (unsigned short)r;
}
__device__ __forceinline__ float bf2f(unsigned short b) {
  return __uint_as_float(((unsigned int)b) << 16);
}

#define MFMA(a, b, c) __builtin_amdgcn_mfma_f32_16x16x32_bf16(a, b, c, 0, 0, 0)

// ---------------------------------------------------------------------------
// 1) bucket placement (R3 layout restored): p = atomicAdd(cnt[r]);
//    se[r*CAP+p]={c,v}. Dense per-row buckets -> 1-2 cache lines per row.
//    [R4 post-mortem: range-splitting fragmented se into 8 cold lines/row
//     under the poison-fill and gutted inner-loop MLP -> +76 us. Reverted.]
// ---------------------------------------------------------------------------
__global__ __launch_bounds__(256) void bucket_kernel(
    const int* __restrict__ r0, const int* __restrict__ c0, const float* __restrict__ v0,
    const int* __restrict__ r1, const int* __restrict__ c1, const float* __restrict__ v1,
    int* __restrict__ cnt0, int* __restrict__ cnt1,
    int2* __restrict__ se0, int2* __restrict__ se1, int E)
{
  int t = blockIdx.x * 256 + threadIdx.x;
  if (t < E) {
    int r = r0[t];
    int p = atomicAdd(&cnt0[r], 1);
    if (p < CAP) se0[(size_t)r * CAP + p] = make_int2(c0[t], __float_as_int(v0[t]));
  } else if (t < 2 * E) {
    int e = t - E;
    int r = r1[e];
    int p = atomicAdd(&cnt1[r], 1);
    if (p < CAP) se1[(size_t)r * CAP + p] = make_int2(c1[e], __float_as_int(v1[e]));
  }
}

// ---------------------------------------------------------------------------
// 2) FUSED gather + LN + bf16 hi/lo pack, dual-branch interleaved gather.
//    One wave per vocab row; lane owns cols h=2*lane, 2*lane+1.
//    R5 change vs R3: the two branches' gather loops are INTERLEAVED so each
//    wave keeps 8 Wn-row loads in flight (4 per branch) instead of 4 --
//    2x memory-level parallelism against L2/L3 latency, zero extra traffic.
//    Quad boundaries, per-branch FMA order, and LN order (branch 0 then 1)
//    are identical to R3 -> per-branch numerics bit-identical.
// ---------------------------------------------------------------------------
__global__ __launch_bounds__(1024) void fused_glp_kernel(
    const float* __restrict__ Wn0, const float* __restrict__ Wn1,
    const float* __restrict__ W0s, const float* __restrict__ W1s,
    const int* __restrict__ cnt0, const int2* __restrict__ se0,
    const int* __restrict__ cnt1, const int2* __restrict__ se1,
    const float* __restrict__ gamma, const float* __restrict__ beta,
    unsigned short* __restrict__ ph, unsigned short* __restrict__ pl, int V)
{
  __shared__ __align__(16) unsigned short lh[2048];   // 4 KB hi half-tile
  __shared__ __align__(16) unsigned short ll[2048];   // 4 KB lo half-tile
  int t = threadIdx.x;
  int wv = t >> 6, lane = t & 63;
  int g = blockIdx.x >> 1, hs = blockIdx.x & 1;

  if (t < 256)      ((f32x4*)lh)[t] = (f32x4)(0.f);
  else if (t < 512) ((f32x4*)ll)[t - 256] = (f32x4)(0.f);
  __syncthreads();

  int v = g * 32 + hs * 16 + wv;
  int h = lane * 2;
  if (v < V) {
    fv2 gm = ((const fv2*)gamma)[lane];
    fv2 bt = ((const fv2*)beta)[lane];

    int n0 = cnt0[v]; if (n0 > CAP) n0 = CAP;
    int n1 = cnt1[v]; if (n1 > CAP) n1 = CAP;
    const int2* sp0 = se0 + (size_t)v * CAP;
    const int2* sp1 = se1 + (size_t)v * CAP;

    float a00 = 0.f, a01 = 0.f, ds0 = 0.f;   // branch 0 accumulators
    float a10 = 0.f, a11 = 0.f, ds1 = 0.f;   // branch 1 accumulators

    #define QUAD0(idx)                                                        \
      { int2 e0 = sp0[idx], e1 = sp0[idx + 1], e2 = sp0[idx + 2], e3 = sp0[idx + 3]; \
        fv2 w0 = ((const fv2*)(Wn0 + (size_t)e0.x * HDIM))[lane];             \
        fv2 w1 = ((const fv2*)(Wn0 + (size_t)e1.x * HDIM))[lane];             \
        fv2 w2 = ((const fv2*)(Wn0 + (size_t)e2.x * HDIM))[lane];             \
        fv2 w3 = ((const fv2*)(Wn0 + (size_t)e3.x * HDIM))[lane];             \
        float f0 = __int_as_float(e0.y), f1 = __int_as_float(e1.y);           \
        float f2 = __int_as_float(e2.y), f3 = __int_as_float(e3.y);           \
        ds0 += (f0 + f1) + (f2 + f3);                                         \
        a00 = fmaf(f0, w0.x, a00); a01 = fmaf(f0, w0.y, a01);                 \
        a00 = fmaf(f1, w1.x, a00); a01 = fmaf(f1, w1.y, a01);                 \
        a00 = fmaf(f2, w2.x, a00); a01 = fmaf(f2, w2.y, a01);                 \
        a00 = fmaf(f3, w3.x, a00); a01 = fmaf(f3, w3.y, a01); }
    #define QUAD1(idx)                                                        \
      { int2 e0 = sp1[idx], e1 = sp1[idx + 1], e2 = sp1[idx + 2], e3 = sp1[idx + 3]; \
        fv2 w0 = ((const fv2*)(Wn1 + (size_t)e0.x * HDIM))[lane];             \
        fv2 w1 = ((const fv2*)(Wn1 + (size_t)e1.x * HDIM))[lane];             \
        fv2 w2 = ((const fv2*)(Wn1 + (size_t)e2.x * HDIM))[lane];             \
        fv2 w3 = ((const fv2*)(Wn1 + (size_t)e3.x * HDIM))[lane];             \
        float f0 = __int_as_float(e0.y), f1 = __int_as_float(e1.y);           \
        float f2 = __int_as_float(e2.y), f3 = __int_as_float(e3.y);           \
        ds1 += (f0 + f1) + (f2 + f3);                                         \
        a10 = fmaf(f0, w0.x, a10); a11 = fmaf(f0, w0.y, a11);                 \
        a10 = fmaf(f1, w1.x, a10); a11 = fmaf(f1, w1.y, a11);                 \
        a10 = fmaf(f2, w2.x, a10); a11 = fmaf(f2, w2.y, a11);                 \
        a10 = fmaf(f3, w3.x, a10); a11 = fmaf(f3, w3.y, a11); }

    int i0 = 0, i1 = 0;
    // joint loop: 8 Wn-row loads in flight (4 per branch)
    while (i0 + 4 <= n0 && i1 + 4 <= n1) {
      QUAD0(i0); QUAD1(i1);
      i0 += 4; i1 += 4;
    }
    // drains (quad boundaries identical to R3's per-branch loops)
    for (; i0 + 4 <= n0; i0 += 4) QUAD0(i0);
    for (; i0 < n0; ++i0) {
      int2 e0 = sp0[i0];
      fv2 w0 = ((const fv2*)(Wn0 + (size_t)e0.x * HDIM))[lane];
      float f0 = __int_as_float(e0.y);
      ds0 += f0;
      a00 = fmaf(f0, w0.x, a00); a01 = fmaf(f0, w0.y, a01);
    }
    for (; i1 + 4 <= n1; i1 += 4) QUAD1(i1);
    for (; i1 < n1; ++i1) {
      int2 e0 = sp1[i1];
      fv2 w0 = ((const fv2*)(Wn1 + (size_t)e0.x * HDIM))[lane];
      float f0 = __int_as_float(e0.y);
      ds1 += f0;
      a10 = fmaf(f0, w0.x, a10); a11 = fmaf(f0, w0.y, a11);
    }
    #undef QUAD0
    #undef QUAD1

    float ry0 = 0.f, ry1 = 0.f;
    #pragma unroll
    for (int br = 0; br < 2; ++br) {       // LN: branch 0 then branch 1 (R3 order)
      float aa0 = br ? a10 : a00;
      float aa1 = br ? a11 : a01;
      float dsum = br ? ds1 : ds0;
      const float* Ws = br ? W1s : W0s;
      float invd = 1.0f / fmaxf(dsum, 1.0f);
      fv2 ww = ((const fv2*)(Ws + (size_t)v * HDIM))[lane];
      float x0 = fmaxf(fmaf(aa0, invd, ww.x), 0.f);
      float x1 = fmaxf(fmaf(aa1, invd, ww.y), 0.f);
      float sum = x0 + x1;
      #pragma unroll
      for (int off = 32; off; off >>= 1) sum += __shfl_xor(sum, off, 64);
      float mu = sum * (1.0f / 128.0f);
      float d0 = x0 - mu, d1 = x1 - mu;
      float q = d0 * d0 + d1 * d1;
      #pragma unroll
      for (int off = 32; off; off >>= 1) q += __shfl_xor(q, off, 64);
      float rstd = rsqrtf(q * (1.0f / 128.0f) + 1e-5f);
      ry0 += d0 * rstd * gm.x + bt.x;
      ry1 += d1 * rstd * gm.y + bt.y;
    }
    // local scatter into half-tile: full-group slot = tt*512 + l*8 + j with
    // l = qq*16 + (h&15), qq = r>>3, j = r&7, r = hs*16+wv; half-local form:
    int tt = lane >> 3;
    int loc = tt * 256 + ((wv >> 3) * 16 + (h & 15)) * 8 + (wv & 7);
    unsigned short h0 = f2bf(ry0);
    unsigned short l0 = f2bf(ry0 - bf2f(h0));
    unsigned short h1 = f2bf(ry1);
    unsigned short l1 = f2bf(ry1 - bf2f(h1));
    lh[loc] = h0;     ll[loc] = l0;
    lh[loc + 8] = h1; ll[loc + 8] = l1;
  }
  __syncthreads();

  // coalesced write-out: half-tile chunk c (16B) -> global chunk
  //   g*512 + (c>>5)*32 + hs*32 + c     (512 B runs, 512 B stride)
  if (t < 512) {
    int arr = t >> 8;            // 0: ph, 1: pl
    int c = t & 255;
    size_t chunk = (size_t)g * 512 + (size_t)(((c >> 5) + hs) * 32 + c);
    f32x4 val = arr ? ((const f32x4*)ll)[c] : ((const f32x4*)lh)[c];
    f32x4* dst = arr ? (f32x4*)pl : (f32x4*)ph;
    dst[chunk] = val;
  }
}

__device__ __forceinline__ void cvt8hi(float4 a0, float4 a1, short8& hi) {
  float vv[8] = {a0.x, a0.y, a0.z, a0.w, a1.x, a1.y, a1.z, a1.w};
  #pragma unroll
  for (int j = 0; j < 8; ++j) hi[j] = (short)f2bf(vv[j]);
}

// ---------------------------------------------------------------------------
// 3) MFMA GEMM: global_load_lds(16B) staging of X (fp32, chunk-XOR swizzled)
//    and pre-packed B hi/lo, double-buffered LDS. 2-term split:
//    X(bf16) x (B_hi + B_lo). BM=128, BN=128, K-step 32. Split-K into P.
//    (unchanged)
// ---------------------------------------------------------------------------
__global__ __launch_bounds__(256, 2) void gemm_kernel(
    const float* __restrict__ X, const unsigned short* __restrict__ ph,
    const unsigned short* __restrict__ pl, float* __restrict__ P,
    int M, int K, int groups, int gps)
{
  __shared__ __align__(16) float Xl[2][128 * 32];            // 16 KB each
  __shared__ __align__(16) unsigned short Bl[2][2][4096];    // hi/lo, 8 KB each
  int t = threadIdx.x;
  int w = t >> 6, lane = t & 63;
  int m0 = blockIdx.x * 128;
  int g0 = blockIdx.y * gps;
  int g1 = g0 + gps; if (g1 > groups) g1 = groups;
  int q = lane >> 4;

  int xr = w * 32 + (lane >> 3);          // local row for staging call j=0 (+8j)
  int xc = lane & 7;                      // 16B chunk index
  int swz = ((xc ^ (xr & 7)) << 2);

  f32x4 acc[2][8];
  #pragma unroll
  for (int rt = 0; rt < 2; ++rt)
    #pragma unroll
    for (int ct = 0; ct < 8; ++ct) acc[rt][ct] = (f32x4)(0.f);

  auto stageX = [&](int g, int buf) {
    int kf = g * 32 + swz;
    bool ok = (kf + 4 <= K);
    const float* rbase = X + (size_t)(m0 + xr) * K + kf;
    #pragma unroll
    for (int j = 0; j < 4; ++j) {
      const float* gp = ok ? (rbase + (size_t)(8 * j) * K) : X;
      gload16(gp, &Xl[buf][(w * 32 + 8 * j) * 32]);
    }
  };
  auto stageB = [&](int g, int buf) {
    const unsigned short* gh = ph + (size_t)g * 4096 + (w * 2) * 512 + lane * 8;
    const unsigned short* gl = pl + (size_t)g * 4096 + (w * 2) * 512 + lane * 8;
    #pragma unroll
    for (int j = 0; j < 2; ++j) {
      gload16(gh + j * 512, &Bl[buf][0][(w * 2 + j) * 512]);
      gload16(gl + j * 512, &Bl[buf][1][(w * 2 + j) * 512]);
    }
  };

  if (g0 < g1) { stageX(g0, 0); stageB(g0, 0); }
  __syncthreads();

  for (int g = g0; g < g1; ++g) {
    int buf = (g - g0) & 1;
    if (g + 1 < g1) { stageX(g + 1, buf ^ 1); stageB(g + 1, buf ^ 1); }
    short8 ah[2];
    #pragma unroll
    for (int rt = 0; rt < 2; ++rt) {
      int arow = w * 32 + rt * 16 + (lane & 15);
      int sx = arow & 7;
      float4 a0 = *(const float4*)&Xl[buf][arow * 32 + (((2 * q) ^ sx) << 2)];
      float4 a1 = *(const float4*)&Xl[buf][arow * 32 + ((((2 * q) | 1) ^ sx) << 2)];
      cvt8hi(a0, a1, ah[rt]);
    }
    #pragma unroll
    for (int ct = 0; ct < 8; ++ct) {
      short8 bh = *(const short8*)&Bl[buf][0][ct * 512 + lane * 8];
      short8 bl = *(const short8*)&Bl[buf][1][ct * 512 + lane * 8];
      #pragma unroll
      for (int rt = 0; rt < 2; ++rt) {
        acc[rt][ct] = MFMA(ah[rt], bh, acc[rt][ct]);
        acc[rt][ct] = MFMA(ah[rt], bl, acc[rt][ct]);
      }
    }
    __syncthreads();
  }

  float* pp = P + (size_t)blockIdx.y * ((size_t)M * 128);
  #pragma unroll
  for (int rt = 0; rt < 2; ++rt) {
    #pragma unroll
    for (int ct = 0; ct < 8; ++ct) {
      int n = ct * 16 + (lane & 15);
      #pragma unroll
      for (int r = 0; r < 4; ++r) {
        int m = m0 + w * 32 + rt * 16 + (lane >> 4) * 4 + r;
        pp[(size_t)m * 128 + n] = acc[rt][ct][r];
      }
    }
  }
}

// ---------------------------------------------------------------------------
// 4) fused split-K reduce + fc: T-row segment reduced in registers (same
//    s=0..S order -> bit-identical), staged through LDS, then
//    out = T @ fc_W + fc_b. (unchanged)
// ---------------------------------------------------------------------------
__global__ __launch_bounds__(256) void fc_kernel(
    const float* __restrict__ P, const float* __restrict__ W,
    const float* __restrict__ bias, float* __restrict__ out, int n, int S)
{
  __shared__ float Wl[HDIM * HDIM];   // 64 KB
  __shared__ float Tl[16 * HDIM];     // 8 KB
  int t = threadIdx.x;
  const float4* Wv = (const float4*)W;
  float4* Wlv = (float4*)Wl;
  #pragma unroll
  for (int i = t; i < HDIM * HDIM / 4; i += 256) Wlv[i] = Wv[i];

  int m_loc = t >> 4;                 // 0..15
  int o = (t & 15) << 3;              // 0,8,..,120
  int m = blockIdx.x * 16 + m_loc;
  size_t base = (size_t)m * HDIM + o;

  float4 tv0 = make_float4(0.f, 0.f, 0.f, 0.f);
  float4 tv1 = make_float4(0.f, 0.f, 0.f, 0.f);
  for (int s = 0; s < S; ++s) {
    const float4* pr = (const float4*)(P + (size_t)s * n + base);
    float4 a = pr[0], b = pr[1];
    tv0.x += a.x; tv0.y += a.y; tv0.z += a.z; tv0.w += a.w;
    tv1.x += b.x; tv1.y += b.y; tv1.z += b.z; tv1.w += b.w;
  }
  ((float4*)&Tl[m_loc * HDIM + o])[0] = tv0;
  ((float4*)&Tl[m_loc * HDIM + o])[1] = tv1;
  __syncthreads();

  float acc[8];
  #pragma unroll
  for (int j = 0; j < 8; ++j) acc[j] = bias[o + j];
  const float* Trow = Tl + m_loc * HDIM;
  for (int k = 0; k < HDIM; ++k) {
    float a = Trow[k];
    const float* wr = &Wl[k * HDIM + o];
    #pragma unroll
    for (int j = 0; j < 8; ++j) acc[j] = fmaf(a, wr[j], acc[j]);
  }
  float* orow = out + (size_t)m * HDIM + o;
  #pragma unroll
  for (int j = 0; j < 8; ++j) orow[j] = acc[j];
}

// ---------------------------------------------------------------------------
extern "C" void kernel_launch(void* const* d_in, const int* in_sizes, int n_in,
                              void* d_out, int out_size, void* d_ws, size_t ws_size,
                              hipStream_t stream) {
  const float* X   = (const float*)d_in[0];
  const float* W0s = (const float*)d_in[1];
  const float* W0n = (const float*)d_in[2];
  const float* W1s = (const float*)d_in[3];
  const float* W1n = (const float*)d_in[4];
  const int*   r0  = (const int*)d_in[5];
  const int*   c0  = (const int*)d_in[6];
  const float* v0  = (const float*)d_in[7];
  const int*   r1  = (const int*)d_in[8];
  const int*   c1  = (const int*)d_in[9];
  const float* v1  = (const float*)d_in[10];
  const float* gam = (const float*)d_in[11];
  const float* bet = (const float*)d_in[12];
  const float* fcW = (const float*)d_in[13];
  const float* fcb = (const float*)d_in[14];
  float* out = (float*)d_out;

  const int H = HDIM;
  const int V = in_sizes[1] / H;     // 30000
  const int B = in_sizes[0] / V;     // 2048
  const int E = in_sizes[5];         // 480000
  const int groups = (V + 31) / 32;  // 938

  // workspace layout (R3)
  char* p = (char*)d_ws;
  int*   cnt0 = (int*)p;               p += (size_t)V * 4;   // memset covers cnt0+cnt1
  int*   cnt1 = (int*)p;               p += (size_t)V * 4;
  unsigned short* ph = (unsigned short*)p;  p += (size_t)groups * 4096 * 2;
  unsigned short* pl = (unsigned short*)p;  p += (size_t)groups * 4096 * 2;
  // region2: se buckets, later aliased by split-K partials P
  char*  region2 = p;
  int2*  se0    = (int2*)region2;                                  // V*CAP*8
  int2*  se1    = se0 + (size_t)V * CAP;                           // V*CAP*8
  float* P      = (float*)region2;     // NSPLIT*B*H*4 = 33.6 MB aliases se

  const int S = NSPLIT;
  const int gps = (groups + S - 1) / S;

  hipMemsetAsync(cnt0, 0, (size_t)V * 2 * 4, stream);

  int eblocks = (2 * E + 255) / 256;
  bucket_kernel<<<eblocks, 256, 0, stream>>>(r0, c0, v0, r1, c1, v1,
                                             cnt0, cnt1, se0, se1, E);
  int fblocks = groups * 2;            // half-groups of 16 rows
  fused_glp_kernel<<<fblocks, 1024, 0, stream>>>(W0n, W1n, W0s, W1s,
                                                 cnt0, se0, cnt1, se1,
                                                 gam, bet, ph, pl, V);
  dim3 ggrid(B / 128, S);
  gemm_kernel<<<ggrid, 256, 0, stream>>>(X, ph, pl, P, B, V, groups, gps);
  fc_kernel<<<B / 16, 256, 0, stream>>>(P, fcW, fcb, out, B * H, S);
}

// Round 6
// 570.358 us; speedup vs baseline: 1.1087x; 1.0158x over previous
//
#include <hip/hip_runtime.h>

typedef short short8 __attribute__((ext_vector_type(8)));
typedef float f32x4 __attribute__((ext_vector_type(4)));
typedef float fv2 __attribute__((ext_vector_type(2)));
typedef unsigned int u32;

#define HDIM 128
#define NSPLIT 32
#define CAP 64          // bucket capacity per row; rows ~Poisson(16), P(>64) ~ 1e-20

#define AS1 __attribute__((address_space(1)))
#define AS3 __attribute__((address_space(3)))

__device__ __forceinline__ void gload16(const void* g, void* l) {
  __builtin_amdgcn_global_load_lds((AS1 const u32*)g, (AS3 u32*)l, 16, 0, 0);
}

__device__ __forceinline__ unsigned short f2bf(float x) {
  unsigned int u = __float_as_uint(x);
  unsigned int r = (u + 0x7fffu + ((u >> 16) & 1u)) >> 16;
  return (unsigned short)r;
}
__device__ __forceinline__ float bf2f(unsigned short b) {
  return __uint_as_float(((unsigned int)b) << 16);
}

#define MFMA(a, b, c) __builtin_amdgcn_mfma_f32_16x16x32_bf16(a, b, c, 0, 0, 0)

// ---------------------------------------------------------------------------
// 1) bucket placement (R3 layout): p = atomicAdd(cnt[r]); se[r*CAP+p]={c,v}.
//    Dense per-row buckets; plain stores (R1: nt hints push se to HBM).
// ---------------------------------------------------------------------------
__global__ __launch_bounds__(256) void bucket_kernel(
    const int* __restrict__ r0, const int* __restrict__ c0, const float* __restrict__ v0,
    const int* __restrict__ r1, const int* __restrict__ c1, const float* __restrict__ v1,
    int* __restrict__ cnt0, int* __restrict__ cnt1,
    int2* __restrict__ se0, int2* __restrict__ se1, int E)
{
  int t = blockIdx.x * 256 + threadIdx.x;
  if (t < E) {
    int r = r0[t];
    int p = atomicAdd(&cnt0[r], 1);
    if (p < CAP) se0[(size_t)r * CAP + p] = make_int2(c0[t], __float_as_int(v0[t]));
  } else if (t < 2 * E) {
    int e = t - E;
    int r = r1[e];
    int p = atomicAdd(&cnt1[r], 1);
    if (p < CAP) se1[(size_t)r * CAP + p] = make_int2(c1[e], __float_as_int(v1[e]));
  }
}

// ---------------------------------------------------------------------------
// 2) FUSED gather + LN + bf16 hi/lo pack -- paired-edge float4 gather.
//    [R5 post-mortem: 2x per-wave loads-in-flight was null -> the per-CU vmem
//     INSTRUCTION queue is the cap, not per-wave MLP. So: halve instructions,
//     not raise depth.]
//    One wave per vocab row. Per gather instruction, lanes 0-31 read float4
//    (16B) of Wn[e_i], lanes 32-63 of Wn[e_{i+1}]: TWO rows (1024 B) per
//    instruction vs one fv2 row before. Lane owns cols 4u..4u+3 (u=lane&31),
//    halves hold even/odd-edge partials; one shfl_xor(32) per branch combines.
//    dsum uses wave-uniform vals on all lanes in R3's exact quad order.
//    LN tree runs over duplicated halves (/256 == /128 on the true sum).
//    Pack layout formula unchanged (generalized to per-col h).
// ---------------------------------------------------------------------------
__global__ __launch_bounds__(1024) void fused_glp_kernel(
    const float* __restrict__ Wn0, const float* __restrict__ Wn1,
    const float* __restrict__ W0s, const float* __restrict__ W1s,
    const int* __restrict__ cnt0, const int2* __restrict__ se0,
    const int* __restrict__ cnt1, const int2* __restrict__ se1,
    const float* __restrict__ gamma, const float* __restrict__ beta,
    unsigned short* __restrict__ ph, unsigned short* __restrict__ pl, int V)
{
  __shared__ __align__(16) unsigned short lh[2048];   // 4 KB hi half-tile
  __shared__ __align__(16) unsigned short ll[2048];   // 4 KB lo half-tile
  int t = threadIdx.x;
  int wv = t >> 6, lane = t & 63;
  int g = blockIdx.x >> 1, hs = blockIdx.x & 1;

  if (t < 256)      ((f32x4*)lh)[t] = (f32x4)(0.f);
  else if (t < 512) ((f32x4*)ll)[t - 256] = (f32x4)(0.f);
  __syncthreads();

  int v = g * 32 + hs * 16 + wv;
  int u = lane & 31;          // column block: cols 4u..4u+3
  int half = lane >> 5;       // 0: even edge of pair, 1: odd edge
  if (v < V) {
    float4 gm = ((const float4*)gamma)[u];
    float4 bt = ((const float4*)beta)[u];
    float ry0 = 0.f, ry1 = 0.f, ry2 = 0.f, ry3 = 0.f;

    #pragma unroll
    for (int br = 0; br < 2; ++br) {
      const float* Wn = br ? Wn1 : Wn0;
      const float* Ws = br ? W1s : W0s;
      const int*  cnt = br ? cnt1 : cnt0;
      const int2* se  = br ? se1 : se0;
      int n = cnt[v]; if (n > CAP) n = CAP;
      const int2* sep = se + (size_t)v * CAP;
      float a0 = 0.f, a1 = 0.f, a2 = 0.f, a3 = 0.f, ds = 0.f;

      int i = 0;
      // 8-edge body: 4 float4 gathers (8 Wn rows) in flight
      for (; i + 8 <= n; i += 8) {
        int2 e0 = sep[i],     e1 = sep[i + 1], e2 = sep[i + 2], e3 = sep[i + 3];
        int2 e4 = sep[i + 4], e5 = sep[i + 5], e6 = sep[i + 6], e7 = sep[i + 7];
        int cA = half ? e1.x : e0.x;
        int cB = half ? e3.x : e2.x;
        int cC = half ? e5.x : e4.x;
        int cD = half ? e7.x : e6.x;
        float4 wA = *(const float4*)(Wn + (size_t)cA * HDIM + (u << 2));
        float4 wB = *(const float4*)(Wn + (size_t)cB * HDIM + (u << 2));
        float4 wC = *(const float4*)(Wn + (size_t)cC * HDIM + (u << 2));
        float4 wD = *(const float4*)(Wn + (size_t)cD * HDIM + (u << 2));
        float f0 = __int_as_float(e0.y), f1 = __int_as_float(e1.y);
        float f2 = __int_as_float(e2.y), f3 = __int_as_float(e3.y);
        float f4 = __int_as_float(e4.y), f5 = __int_as_float(e5.y);
        float f6 = __int_as_float(e6.y), f7 = __int_as_float(e7.y);
        ds += (f0 + f1) + (f2 + f3);          // R3 quad order
        ds += (f4 + f5) + (f6 + f7);
        float fA = half ? f1 : f0;
        float fB = half ? f3 : f2;
        float fC = half ? f5 : f4;
        float fD = half ? f7 : f6;
        a0 = fmaf(fA, wA.x, a0); a1 = fmaf(fA, wA.y, a1);
        a2 = fmaf(fA, wA.z, a2); a3 = fmaf(fA, wA.w, a3);
        a0 = fmaf(fB, wB.x, a0); a1 = fmaf(fB, wB.y, a1);
        a2 = fmaf(fB, wB.z, a2); a3 = fmaf(fB, wB.w, a3);
        a0 = fmaf(fC, wC.x, a0); a1 = fmaf(fC, wC.y, a1);
        a2 = fmaf(fC, wC.z, a2); a3 = fmaf(fC, wC.w, a3);
        a0 = fmaf(fD, wD.x, a0); a1 = fmaf(fD, wD.y, a1);
        a2 = fmaf(fD, wD.z, a2); a3 = fmaf(fD, wD.w, a3);
      }
      // 4-edge body (2 gathers)
      for (; i + 4 <= n; i += 4) {
        int2 e0 = sep[i], e1 = sep[i + 1], e2 = sep[i + 2], e3 = sep[i + 3];
        int cA = half ? e1.x : e0.x;
        int cB = half ? e3.x : e2.x;
        float4 wA = *(const float4*)(Wn + (size_t)cA * HDIM + (u << 2));
        float4 wB = *(const float4*)(Wn + (size_t)cB * HDIM + (u << 2));
        float f0 = __int_as_float(e0.y), f1 = __int_as_float(e1.y);
        float f2 = __int_as_float(e2.y), f3 = __int_as_float(e3.y);
        ds += (f0 + f1) + (f2 + f3);
        float fA = half ? f1 : f0;
        float fB = half ? f3 : f2;
        a0 = fmaf(fA, wA.x, a0); a1 = fmaf(fA, wA.y, a1);
        a2 = fmaf(fA, wA.z, a2); a3 = fmaf(fA, wA.w, a3);
        a0 = fmaf(fB, wB.x, a0); a1 = fmaf(fB, wB.y, a1);
        a2 = fmaf(fB, wB.z, a2); a3 = fmaf(fB, wB.w, a3);
      }
      // pairwise tail (1-3 edges), f=0 pad keeps math exact
      for (; i < n; i += 2) {
        int2 e0 = sep[i];
        int has1 = (i + 1 < n);
        int2 e1 = has1 ? sep[i + 1] : e0;
        float f0 = __int_as_float(e0.y);
        float f1v = has1 ? __int_as_float(e1.y) : 0.f;
        int cA = half ? e1.x : e0.x;
        float fA = half ? f1v : f0;
        float4 wA = *(const float4*)(Wn + (size_t)cA * HDIM + (u << 2));
        ds += f0;
        if (has1) ds += f1v;
        a0 = fmaf(fA, wA.x, a0); a1 = fmaf(fA, wA.y, a1);
        a2 = fmaf(fA, wA.z, a2); a3 = fmaf(fA, wA.w, a3);
      }
      // combine even/odd halves -> full column sums on every lane
      a0 += __shfl_xor(a0, 32, 64);
      a1 += __shfl_xor(a1, 32, 64);
      a2 += __shfl_xor(a2, 32, 64);
      a3 += __shfl_xor(a3, 32, 64);

      float invd = 1.0f / fmaxf(ds, 1.0f);
      float4 ww = ((const float4*)(Ws + (size_t)v * HDIM))[u];
      float x0 = fmaxf(fmaf(a0, invd, ww.x), 0.f);
      float x1 = fmaxf(fmaf(a1, invd, ww.y), 0.f);
      float x2 = fmaxf(fmaf(a2, invd, ww.z), 0.f);
      float x3 = fmaxf(fmaf(a3, invd, ww.w), 0.f);
      float sum = (x0 + x1) + (x2 + x3);
      #pragma unroll
      for (int off = 32; off; off >>= 1) sum += __shfl_xor(sum, off, 64);
      float mu = sum * (1.0f / 256.0f);       // halves duplicated -> /256
      float d0 = x0 - mu, d1 = x1 - mu, d2 = x2 - mu, d3 = x3 - mu;
      float q = (d0 * d0 + d1 * d1) + (d2 * d2 + d3 * d3);
      #pragma unroll
      for (int off = 32; off; off >>= 1) q += __shfl_xor(q, off, 64);
      float rstd = rsqrtf(q * (1.0f / 256.0f) + 1e-5f);
      ry0 += d0 * rstd * gm.x + bt.x;
      ry1 += d1 * rstd * gm.y + bt.y;
      ry2 += d2 * rstd * gm.z + bt.z;
      ry3 += d3 * rstd * gm.w + bt.w;
    }

    // pack: lane<32 writes its 4 cols (lanes>=32 hold duplicates)
    if (lane < 32) {
      float ry[4] = {ry0, ry1, ry2, ry3};
      #pragma unroll
      for (int c = 0; c < 4; ++c) {
        int h = (u << 2) + c;
        int tt = h >> 4;
        int loc = tt * 256 + ((wv >> 3) * 16 + (h & 15)) * 8 + (wv & 7);
        unsigned short hi = f2bf(ry[c]);
        unsigned short lo = f2bf(ry[c] - bf2f(hi));
        lh[loc] = hi; ll[loc] = lo;
      }
    }
  }
  __syncthreads();

  // coalesced write-out: half-tile chunk c (16B) -> global chunk
  //   g*512 + (c>>5)*32 + hs*32 + c     (512 B runs, 512 B stride)
  if (t < 512) {
    int arr = t >> 8;            // 0: ph, 1: pl
    int c = t & 255;
    size_t chunk = (size_t)g * 512 + (size_t)(((c >> 5) + hs) * 32 + c);
    f32x4 val = arr ? ((const f32x4*)ll)[c] : ((const f32x4*)lh)[c];
    f32x4* dst = arr ? (f32x4*)pl : (f32x4*)ph;
    dst[chunk] = val;
  }
}

__device__ __forceinline__ void cvt8hi(float4 a0, float4 a1, short8& hi) {
  float vv[8] = {a0.x, a0.y, a0.z, a0.w, a1.x, a1.y, a1.z, a1.w};
  #pragma unroll
  for (int j = 0; j < 8; ++j) hi[j] = (short)f2bf(vv[j]);
}

// ---------------------------------------------------------------------------
// 3) MFMA GEMM: global_load_lds(16B) staging of X (fp32, chunk-XOR swizzled)
//    and pre-packed B hi/lo, double-buffered LDS. 2-term split:
//    X(bf16) x (B_hi + B_lo). BM=128, BN=128, K-step 32. Split-K into P.
//    (unchanged)
// ---------------------------------------------------------------------------
__global__ __launch_bounds__(256, 2) void gemm_kernel(
    const float* __restrict__ X, const unsigned short* __restrict__ ph,
    const unsigned short* __restrict__ pl, float* __restrict__ P,
    int M, int K, int groups, int gps)
{
  __shared__ __align__(16) float Xl[2][128 * 32];            // 16 KB each
  __shared__ __align__(16) unsigned short Bl[2][2][4096];    // hi/lo, 8 KB each
  int t = threadIdx.x;
  int w = t >> 6, lane = t & 63;
  int m0 = blockIdx.x * 128;
  int g0 = blockIdx.y * gps;
  int g1 = g0 + gps; if (g1 > groups) g1 = groups;
  int q = lane >> 4;

  int xr = w * 32 + (lane >> 3);          // local row for staging call j=0 (+8j)
  int xc = lane & 7;                      // 16B chunk index
  int swz = ((xc ^ (xr & 7)) << 2);

  f32x4 acc[2][8];
  #pragma unroll
  for (int rt = 0; rt < 2; ++rt)
    #pragma unroll
    for (int ct = 0; ct < 8; ++ct) acc[rt][ct] = (f32x4)(0.f);

  auto stageX = [&](int g, int buf) {
    int kf = g * 32 + swz;
    bool ok = (kf + 4 <= K);
    const float* rbase = X + (size_t)(m0 + xr) * K + kf;
    #pragma unroll
    for (int j = 0; j < 4; ++j) {
      const float* gp = ok ? (rbase + (size_t)(8 * j) * K) : X;
      gload16(gp, &Xl[buf][(w * 32 + 8 * j) * 32]);
    }
  };
  auto stageB = [&](int g, int buf) {
    const unsigned short* gh = ph + (size_t)g * 4096 + (w * 2) * 512 + lane * 8;
    const unsigned short* gl = pl + (size_t)g * 4096 + (w * 2) * 512 + lane * 8;
    #pragma unroll
    for (int j = 0; j < 2; ++j) {
      gload16(gh + j * 512, &Bl[buf][0][(w * 2 + j) * 512]);
      gload16(gl + j * 512, &Bl[buf][1][(w * 2 + j) * 512]);
    }
  };

  if (g0 < g1) { stageX(g0, 0); stageB(g0, 0); }
  __syncthreads();

  for (int g = g0; g < g1; ++g) {
    int buf = (g - g0) & 1;
    if (g + 1 < g1) { stageX(g + 1, buf ^ 1); stageB(g + 1, buf ^ 1); }
    short8 ah[2];
    #pragma unroll
    for (int rt = 0; rt < 2; ++rt) {
      int arow = w * 32 + rt * 16 + (lane & 15);
      int sx = arow & 7;
      float4 a0 = *(const float4*)&Xl[buf][arow * 32 + (((2 * q) ^ sx) << 2)];
      float4 a1 = *(const float4*)&Xl[buf][arow * 32 + ((((2 * q) | 1) ^ sx) << 2)];
      cvt8hi(a0, a1, ah[rt]);
    }
    #pragma unroll
    for (int ct = 0; ct < 8; ++ct) {
      short8 bh = *(const short8*)&Bl[buf][0][ct * 512 + lane * 8];
      short8 bl = *(const short8*)&Bl[buf][1][ct * 512 + lane * 8];
      #pragma unroll
      for (int rt = 0; rt < 2; ++rt) {
        acc[rt][ct] = MFMA(ah[rt], bh, acc[rt][ct]);
        acc[rt][ct] = MFMA(ah[rt], bl, acc[rt][ct]);
      }
    }
    __syncthreads();
  }

  float* pp = P + (size_t)blockIdx.y * ((size_t)M * 128);
  #pragma unroll
  for (int rt = 0; rt < 2; ++rt) {
    #pragma unroll
    for (int ct = 0; ct < 8; ++ct) {
      int n = ct * 16 + (lane & 15);
      #pragma unroll
      for (int r = 0; r < 4; ++r) {
        int m = m0 + w * 32 + rt * 16 + (lane >> 4) * 4 + r;
        pp[(size_t)m * 128 + n] = acc[rt][ct][r];
      }
    }
  }
}

// ---------------------------------------------------------------------------
// 4) fused split-K reduce + fc: T-row segment reduced in registers (same
//    s=0..S order -> bit-identical), staged through LDS, then
//    out = T @ fc_W + fc_b. (unchanged)
// ---------------------------------------------------------------------------
__global__ __launch_bounds__(256) void fc_kernel(
    const float* __restrict__ P, const float* __restrict__ W,
    const float* __restrict__ bias, float* __restrict__ out, int n, int S)
{
  __shared__ float Wl[HDIM * HDIM];   // 64 KB
  __shared__ float Tl[16 * HDIM];     // 8 KB
  int t = threadIdx.x;
  const float4* Wv = (const float4*)W;
  float4* Wlv = (float4*)Wl;
  #pragma unroll
  for (int i = t; i < HDIM * HDIM / 4; i += 256) Wlv[i] = Wv[i];

  int m_loc = t >> 4;                 // 0..15
  int o = (t & 15) << 3;              // 0,8,..,120
  int m = blockIdx.x * 16 + m_loc;
  size_t base = (size_t)m * HDIM + o;

  float4 tv0 = make_float4(0.f, 0.f, 0.f, 0.f);
  float4 tv1 = make_float4(0.f, 0.f, 0.f, 0.f);
  for (int s = 0; s < S; ++s) {
    const float4* pr = (const float4*)(P + (size_t)s * n + base);
    float4 a = pr[0], b = pr[1];
    tv0.x += a.x; tv0.y += a.y; tv0.z += a.z; tv0.w += a.w;
    tv1.x += b.x; tv1.y += b.y; tv1.z += b.z; tv1.w += b.w;
  }
  ((float4*)&Tl[m_loc * HDIM + o])[0] = tv0;
  ((float4*)&Tl[m_loc * HDIM + o])[1] = tv1;
  __syncthreads();

  float acc[8];
  #pragma unroll
  for (int j = 0; j < 8; ++j) acc[j] = bias[o + j];
  const float* Trow = Tl + m_loc * HDIM;
  for (int k = 0; k < HDIM; ++k) {
    float a = Trow[k];
    const float* wr = &Wl[k * HDIM + o];
    #pragma unroll
    for (int j = 0; j < 8; ++j) acc[j] = fmaf(a, wr[j], acc[j]);
  }
  float* orow = out + (size_t)m * HDIM + o;
  #pragma unroll
  for (int j = 0; j < 8; ++j) orow[j] = acc[j];
}

// ---------------------------------------------------------------------------
extern "C" void kernel_launch(void* const* d_in, const int* in_sizes, int n_in,
                              void* d_out, int out_size, void* d_ws, size_t ws_size,
                              hipStream_t stream) {
  const float* X   = (const float*)d_in[0];
  const float* W0s = (const float*)d_in[1];
  const float* W0n = (const float*)d_in[2];
  const float* W1s = (const float*)d_in[3];
  const float* W1n = (const float*)d_in[4];
  const int*   r0  = (const int*)d_in[5];
  const int*   c0  = (const int*)d_in[6];
  const float* v0  = (const float*)d_in[7];
  const int*   r1  = (const int*)d_in[8];
  const int*   c1  = (const int*)d_in[9];
  const float* v1  = (const float*)d_in[10];
  const float* gam = (const float*)d_in[11];
  const float* bet = (const float*)d_in[12];
  const float* fcW = (const float*)d_in[13];
  const float* fcb = (const float*)d_in[14];
  float* out = (float*)d_out;

  const int H = HDIM;
  const int V = in_sizes[1] / H;     // 30000
  const int B = in_sizes[0] / V;     // 2048
  const int E = in_sizes[5];         // 480000
  const int groups = (V + 31) / 32;  // 938

  // workspace layout (R3)
  char* p = (char*)d_ws;
  int*   cnt0 = (int*)p;               p += (size_t)V * 4;   // memset covers cnt0+cnt1
  int*   cnt1 = (int*)p;               p += (size_t)V * 4;
  unsigned short* ph = (unsigned short*)p;  p += (size_t)groups * 4096 * 2;
  unsigned short* pl = (unsigned short*)p;  p += (size_t)groups * 4096 * 2;
  // region2: se buckets, later aliased by split-K partials P
  char*  region2 = p;
  int2*  se0    = (int2*)region2;                                  // V*CAP*8
  int2*  se1    = se0 + (size_t)V * CAP;                           // V*CAP*8
  float* P      = (float*)region2;     // NSPLIT*B*H*4 = 33.6 MB aliases se

  const int S = NSPLIT;
  const int gps = (groups + S - 1) / S;

  hipMemsetAsync(cnt0, 0, (size_t)V * 2 * 4, stream);

  int eblocks = (2 * E + 255) / 256;
  bucket_kernel<<<eblocks, 256, 0, stream>>>(r0, c0, v0, r1, c1, v1,
                                             cnt0, cnt1, se0, se1, E);
  int fblocks = groups * 2;            // half-groups of 16 rows
  fused_glp_kernel<<<fblocks, 1024, 0, stream>>>(W0n, W1n, W0s, W1s,
                                                 cnt0, se0, cnt1, se1,
                                                 gam, bet, ph, pl, V);
  dim3 ggrid(B / 128, S);
  gemm_kernel<<<ggrid, 256, 0, stream>>>(X, ph, pl, P, B, V, groups, gps);
  fc_kernel<<<B / 16, 256, 0, stream>>>(P, fcW, fcb, out, B * H, S);
}